// Round 7
// baseline (414.706 us; speedup 1.0000x reference)
//
#include <hip/hip_runtime.h>

#define N_NODES 50000
#define N_EDGES 800000
#define DIM 256
#define HEADS 8
#define NEG_SLOPE 0.2f
#define MAXDEG 64
#define OVFCAP 65536

typedef unsigned short u16;
typedef float floatx4 __attribute__((ext_vector_type(4)));
typedef __bf16 bf16x8 __attribute__((ext_vector_type(8)));

__device__ __forceinline__ float b2f(u16 u) {
    union { unsigned int i; float f; } v; v.i = ((unsigned int)u) << 16; return v.f;
}
__device__ __forceinline__ u16 f2b(float f) {
    union { float f; unsigned int i; } v; v.f = f;
    unsigned int x = v.i;
    if ((x & 0x7f800000u) == 0x7f800000u && (x & 0x007fffffu)) {
        return (u16)((x >> 16) | 0x0040u);
    }
    unsigned int r = (x + 0x7fffu + ((x >> 16) & 1u)) >> 16;
    return (u16)r;
}

__global__ __launch_bounds__(256) void fill_u32(unsigned int* __restrict__ p,
                                                unsigned int v, int n) {
    int i = blockIdx.x * 256 + threadIdx.x;
    if (i < n) p[i] = v;
}

// ---- init: zero counts everywhere; block 0 additionally detects dtype ----
__global__ __launch_bounds__(256) void init_kernel(const unsigned int* __restrict__ d,
                                                   int* __restrict__ counts,
                                                   int* __restrict__ flag,
                                                   int* __restrict__ novf) {
    int i = blockIdx.x * 256 + threadIdx.x;
    if (i < N_NODES) counts[i] = 0;
    if (blockIdx.x == 0) {
        __shared__ int cnt;
        if (threadIdx.x == 0) { cnt = 0; *novf = 0; }
        __syncthreads();
        unsigned int w = d[threadIdx.x];
        int bad = 0;
        #pragma unroll
        for (int half = 0; half < 2; ++half) {
            u16 u = (u16)(w >> (16 * half));
            unsigned int e = (u >> 7) & 0xFFu;
            if (u != 0 && (e >= 141u || e <= 27u)) bad = 1;
        }
        atomicAdd(&cnt, bad);
        __syncthreads();
        if (threadIdx.x == 0) *flag = (cnt > 64) ? 1 : 0;   // 1 = fp32 inputs
    }
}

// ---- prep: 32 blocks, LDS-tiled W1/W2 transpose->bf16 ----
__global__ __launch_bounds__(256) void prep_kernel(const void* __restrict__ W1,
                                                   const void* __restrict__ W2,
                                                   u16* __restrict__ Wt1,
                                                   u16* __restrict__ Wt2,
                                                   const int* __restrict__ flagp) {
    const int isf = *flagp;
    int b = blockIdx.x;
    const void* W = (b < 16) ? W1 : W2;
    u16* Wt = (b < 16) ? Wt1 : Wt2;
    int t = b & 15;
    int k0 = (t >> 2) * 64, n0 = (t & 3) * 64;
    __shared__ float lt[64][65];
    int c = threadIdx.x & 63, r0 = threadIdx.x >> 6;
    #pragma unroll
    for (int j = 0; j < 16; ++j) {
        int r = j * 4 + r0;
        lt[r][c] = isf ? ((const float*)W)[(k0 + r) * 256 + n0 + c]
                       : b2f(((const u16*)W)[(k0 + r) * 256 + n0 + c]);
    }
    __syncthreads();
    #pragma unroll
    for (int j = 0; j < 16; ++j) {
        int rn = j * 4 + r0;
        Wt[(n0 + rn) * 256 + k0 + c] = f2b(lt[c][rn]);   // Wt[n][k]=W[k][n]
    }
}

// ---------------- CSR build (fallback path) ----------------
__global__ __launch_bounds__(256) void hist_kernel(const int* __restrict__ dst,
                                                   int* __restrict__ counts, int E) {
    int i = blockIdx.x * 256 + threadIdx.x;
    if (i < E) atomicAdd(&counts[dst[i]], 1);
}

__global__ __launch_bounds__(256) void scan_partial(const int* __restrict__ counts,
                                                    int* __restrict__ partial, int n) {
    int b = blockIdx.x, tid = threadIdx.x;
    int base = b * 1024 + tid * 4;
    int s = 0;
    #pragma unroll
    for (int k = 0; k < 4; ++k) if (base + k < n) s += counts[base + k];
    int lane = tid & 63;
    #pragma unroll
    for (int off = 32; off; off >>= 1) s += __shfl_xor(s, off);
    __shared__ int wsum[4];
    if (lane == 0) wsum[tid >> 6] = s;
    __syncthreads();
    if (tid == 0) partial[b] = wsum[0] + wsum[1] + wsum[2] + wsum[3];
}

__global__ __launch_bounds__(64) void scan_offsets(const int* __restrict__ partial,
                                                   int* __restrict__ offsets,
                                                   int* __restrict__ row_ptr,
                                                   int nb, int n) {
    int t = threadIdx.x;
    int v0 = (t < nb) ? partial[t] : 0;
    int v = v0;
    #pragma unroll
    for (int d = 1; d < 64; d <<= 1) {
        int u = __shfl_up(v, d);
        if (t >= d) v += u;
    }
    if (t < nb) offsets[t] = v - v0;
    if (t == 63) row_ptr[n] = v;
}

__global__ __launch_bounds__(256) void scan_write(const int* __restrict__ counts,
                                                  const int* __restrict__ offsets,
                                                  int* __restrict__ row_ptr,
                                                  int* __restrict__ wptr, int n) {
    int b = blockIdx.x, tid = threadIdx.x;
    int base = b * 1024 + tid * 4;
    int v[4]; int s = 0;
    #pragma unroll
    for (int k = 0; k < 4; ++k) { v[k] = (base + k < n) ? counts[base + k] : 0; s += v[k]; }
    int lane = tid & 63, w = tid >> 6;
    int incl = s;
    #pragma unroll
    for (int d = 1; d < 64; d <<= 1) {
        int u = __shfl_up(incl, d);
        if (lane >= d) incl += u;
    }
    __shared__ int wsum[4];
    if (lane == 63) wsum[w] = incl;
    __syncthreads();
    int woff = 0;
    for (int i = 0; i < w; ++i) woff += wsum[i];
    int run = offsets[b] + woff + incl - s;
    #pragma unroll
    for (int k = 0; k < 4; ++k) {
        if (base + k < n) { row_ptr[base + k] = run; wptr[base + k] = run; run += v[k]; }
    }
}

__global__ __launch_bounds__(256) void scatter_kernel(const int* __restrict__ src,
                                                      const int* __restrict__ dst,
                                                      int* __restrict__ wptr,
                                                      int* __restrict__ src_sorted, int E) {
    int i = blockIdx.x * 256 + threadIdx.x;
    if (i < E) {
        int pos = atomicAdd(&wptr[dst[i]], 1);
        src_sorted[pos] = src[i];
    }
}

// ---- GEMM body: 32-row x 256-col block, 4 waves (each 32 rows x 64 cols) ----
// No LDS, no barriers. A-fragments direct from global (L2-absorbed redundancy),
// B-fragments from L2-resident Wt. Both register double-buffered.
__device__ __forceinline__ void gemm_body(int gid, const void* __restrict__ Araw,
                                          int maybe_f32,
                                          const u16* __restrict__ Wt,
                                          u16* __restrict__ outF,
                                          float* __restrict__ el,
                                          float* __restrict__ er,
                                          const void* __restrict__ al,
                                          const void* __restrict__ ar,
                                          int M, int isf) {
    const bool af32 = (maybe_f32 != 0) && (isf != 0);
    const int tid  = threadIdx.x;
    const int w    = tid >> 6;       // wave: n-quarter (cols 64w..64w+63, heads 2w,2w+1)
    const int lane = tid & 63;
    const int quad = lane >> 4;
    const int l16  = lane & 15;
    const int m0   = gid * 32;

    const u16* wbase = Wt + (size_t)(64 * w + l16) * 256 + quad * 8;
    const float* Af = (const float*)Araw;
    const u16* Ab = (const u16*)Araw;
    const int rbase = m0 + l16;      // A row for frag i: rbase + 16*i

    u16 zb[8] = {};
    const bf16x8 ZERO = *(const bf16x8*)zb;

    bf16x8 aC[2], aN[2], bC[4], bN[4];
    floatx4 acc[2][4] = {};

#define LOADB(s, dstb) { \
    _Pragma("unroll") \
    for (int t = 0; t < 4; ++t) \
        dstb[t] = *(const bf16x8*)(wbase + (size_t)t * 16 * 256 + (s) * 32); }

#define LOADA(s, dsta) { \
    _Pragma("unroll") \
    for (int i = 0; i < 2; ++i) { \
        int row_ = rbase + 16 * i; \
        if (row_ < M) { \
            if (af32) { \
                const float* p_ = Af + (size_t)row_ * 256 + (s) * 32 + quad * 8; \
                float4 f0_ = *(const float4*)p_; \
                float4 f1_ = *(const float4*)(p_ + 4); \
                u16 tb_[8] = {f2b(f0_.x), f2b(f0_.y), f2b(f0_.z), f2b(f0_.w), \
                              f2b(f1_.x), f2b(f1_.y), f2b(f1_.z), f2b(f1_.w)}; \
                dsta[i] = *(const bf16x8*)tb_; \
            } else { \
                dsta[i] = *(const bf16x8*)(Ab + (size_t)row_ * 256 + (s) * 32 + quad * 8); \
            } \
        } else dsta[i] = ZERO; } }

    LOADB(0, bC);
    LOADA(0, aC);

    #pragma unroll
    for (int s = 0; s < 8; ++s) {
        if (s < 7) { LOADB(s + 1, bN); LOADA(s + 1, aN); }
        #pragma unroll
        for (int i = 0; i < 2; ++i)
            #pragma unroll
            for (int t = 0; t < 4; ++t)
                acc[i][t] = __builtin_amdgcn_mfma_f32_16x16x32_bf16(aC[i], bC[t], acc[i][t], 0, 0, 0);
        if (s < 7) {
            #pragma unroll
            for (int t = 0; t < 4; ++t) bC[t] = bN[t];
            #pragma unroll
            for (int i = 0; i < 2; ++i) aC[i] = aN[i];
        }
    }
#undef LOADA
#undef LOADB

    // C/D: col = l16, row = quad*4+r (within 16x16 slice)
    #pragma unroll
    for (int i = 0; i < 2; ++i)
        #pragma unroll
        for (int t = 0; t < 4; ++t)
            #pragma unroll
            for (int r = 0; r < 4; ++r) {
                int row = m0 + 16 * i + quad * 4 + r;
                if (row < M) outF[(size_t)row * 256 + 64 * w + 16 * t + l16] = f2b(acc[i][t][r]);
            }

    // fused el/er: wave w covers heads 2w, 2w+1
    float alv[4], arv[4];
    #pragma unroll
    for (int t = 0; t < 4; ++t) {
        int c = 64 * w + 16 * t + l16;
        alv[t] = isf ? ((const float*)al)[c] : b2f(((const u16*)al)[c]);
        arv[t] = isf ? ((const float*)ar)[c] : b2f(((const u16*)ar)[c]);
    }
    #pragma unroll
    for (int i = 0; i < 2; ++i)
        #pragma unroll
        for (int r = 0; r < 4; ++r) {
            int row = m0 + 16 * i + quad * 4 + r;
            #pragma unroll
            for (int tt = 0; tt < 2; ++tt) {
                float pl = acc[i][2 * tt][r] * alv[2 * tt] + acc[i][2 * tt + 1][r] * alv[2 * tt + 1];
                float pr = acc[i][2 * tt][r] * arv[2 * tt] + acc[i][2 * tt + 1][r] * arv[2 * tt + 1];
                #pragma unroll
                for (int mask = 1; mask <= 8; mask <<= 1) {
                    pl += __shfl_xor(pl, mask);
                    pr += __shfl_xor(pr, mask);
                }
                if (l16 == 0 && row < M) {
                    el[row * 8 + 2 * w + tt] = pl;
                    er[row * 8 + 2 * w + tt] = pr;
                }
            }
        }
}

__global__ __launch_bounds__(256, 4) void gemm_kernel(const void* __restrict__ Araw,
                                                      int maybe_f32,
                                                      const u16* __restrict__ Wt,
                                                      u16* __restrict__ outF,
                                                      float* __restrict__ el,
                                                      float* __restrict__ er,
                                                      const void* __restrict__ al,
                                                      const void* __restrict__ ar,
                                                      int M, const int* __restrict__ flagp) {
    gemm_body(blockIdx.x, Araw, maybe_f32, Wt, outF, el, er, al, ar, M, *flagp);
}

// ---- fused: interleaved [gemm,gemm,build] block roles; build does 4 edges/thread ----
__global__ __launch_bounds__(256, 4) void gemm_build_kernel(const void* __restrict__ Araw,
                                                            int maybe_f32,
                                                            const u16* __restrict__ Wt,
                                                            u16* __restrict__ outF,
                                                            float* __restrict__ el,
                                                            float* __restrict__ er,
                                                            const void* __restrict__ al,
                                                            const void* __restrict__ ar,
                                                            int M, const int* __restrict__ flagp,
                                                            const int* __restrict__ src,
                                                            const int* __restrict__ dst,
                                                            int* __restrict__ counts,
                                                            int* __restrict__ padded,
                                                            int* __restrict__ novf,
                                                            int2* __restrict__ ovf,
                                                            int E, int GB) {
    const int bx = blockIdx.x;
    const int r3 = bx % 3;
    if (r3 == 2) {
        int base = (bx / 3) * 1024 + threadIdx.x * 4;
        if (base + 3 < E) {
            int4 d4 = *(const int4*)(dst + base);
            int4 s4 = *(const int4*)(src + base);
            int p0 = atomicAdd(&counts[d4.x], 1);
            int p1 = atomicAdd(&counts[d4.y], 1);
            int p2 = atomicAdd(&counts[d4.z], 1);
            int p3 = atomicAdd(&counts[d4.w], 1);
            if (p0 < MAXDEG) padded[d4.x * MAXDEG + p0] = s4.x;
            else { int oi = atomicAdd(novf, 1); if (oi < OVFCAP) { int2 pr; pr.x = d4.x; pr.y = s4.x; ovf[oi] = pr; } }
            if (p1 < MAXDEG) padded[d4.y * MAXDEG + p1] = s4.y;
            else { int oi = atomicAdd(novf, 1); if (oi < OVFCAP) { int2 pr; pr.x = d4.y; pr.y = s4.y; ovf[oi] = pr; } }
            if (p2 < MAXDEG) padded[d4.z * MAXDEG + p2] = s4.z;
            else { int oi = atomicAdd(novf, 1); if (oi < OVFCAP) { int2 pr; pr.x = d4.z; pr.y = s4.z; ovf[oi] = pr; } }
            if (p3 < MAXDEG) padded[d4.w * MAXDEG + p3] = s4.w;
            else { int oi = atomicAdd(novf, 1); if (oi < OVFCAP) { int2 pr; pr.x = d4.w; pr.y = s4.w; ovf[oi] = pr; } }
        } else {
            for (int k = 0; k < 4; ++k) {
                int i = base + k;
                if (i < E) {
                    int d = dst[i], s = src[i];
                    int pos = atomicAdd(&counts[d], 1);
                    if (pos < MAXDEG) padded[d * MAXDEG + pos] = s;
                    else { int oi = atomicAdd(novf, 1); if (oi < OVFCAP) { int2 pr; pr.x = d; pr.y = s; ovf[oi] = pr; } }
                }
            }
        }
    } else {
        int gid = (bx / 3) * 2 + r3;
        if (gid < GB)
            gemm_body(gid, Araw, maybe_f32, Wt, outF, el, er, al, ar, M, *flagp);
    }
}

// ---- aggregate: 1 wave/node; pmode=1 padded buckets, pmode=0 CSR ----
__global__ __launch_bounds__(256) void aggregate_kernel(const u16* __restrict__ feat,
                                                        const float* __restrict__ el,
                                                        const float* __restrict__ er,
                                                        const void* __restrict__ bias,
                                                        const int* __restrict__ idxinfo,
                                                        const int* __restrict__ srcbuf,
                                                        void* __restrict__ out,
                                                        int out_mode,
                                                        int node0,
                                                        const int* __restrict__ flagp,
                                                        int pmode,
                                                        const int* __restrict__ novfp,
                                                        const int2* __restrict__ ovf) {
    const int isf = *flagp;
    const int lane = threadIdx.x & 63;
    const int node = node0 + blockIdx.x * 4 + (threadIdx.x >> 6);
    if (node >= N_NODES) return;
    const int h = lane >> 3;
    const int j = lane & 7;
    int beg, deg;
    if (pmode) { beg = node * MAXDEG; deg = idxinfo[node]; }
    else       { beg = idxinfo[node]; deg = idxinfo[node + 1] - beg; }
    const int dcap = (pmode && deg > MAXDEG) ? MAXDEG : deg;
    int nov = 0;
    if (pmode && deg > MAXDEG) { nov = *novfp; if (nov > OVFCAP) nov = OVFCAP; }
    const float ern = er[node * HEADS + h];

    // ---- phase 1: online softmax, 2 independent accumulators (ILP) ----
    float m0v = -1e30f, ss0 = 0.f;
    float m1v = -1e30f, ss1 = 0.f;
    for (int i = j; i < dcap; i += 16) {
        int s0 = srcbuf[beg + i];
        int i2 = i + 8;
        int s1 = (i2 < dcap) ? srcbuf[beg + i2] : 0;
        float e0 = el[s0 * 8 + h] + ern;
        float e1 = el[s1 * 8 + h] + ern;
        e0 = e0 > 0.f ? e0 : NEG_SLOPE * e0;
        e1 = e1 > 0.f ? e1 : NEG_SLOPE * e1;
        if (i2 >= dcap) e1 = -3e30f;
        float mn0 = fmaxf(m0v, e0);
        ss0 = ss0 * __expf(m0v - mn0) + __expf(e0 - mn0);
        m0v = mn0;
        float mn1 = fmaxf(m1v, e1);
        ss1 = ss1 * __expf(m1v - mn1) + __expf(e1 - mn1);
        m1v = mn1;
    }
    for (int k = j; k < nov; k += 8) {       // rare overflow edges
        int2 pr = ovf[k];
        if (pr.x != node) continue;
        float e = el[pr.y * 8 + h] + ern;
        e = e > 0.f ? e : NEG_SLOPE * e;
        float mn = fmaxf(m0v, e);
        ss0 = ss0 * __expf(m0v - mn) + __expf(e - mn);
        m0v = mn;
    }
    float m = fmaxf(m0v, m1v);
    float ssum = ss0 * __expf(m0v - m) + ss1 * __expf(m1v - m);
    #pragma unroll
    for (int mask = 1; mask <= 4; mask <<= 1) {
        float mo = __shfl_xor(m, mask);
        float so = __shfl_xor(ssum, mask);
        float mn = fmaxf(m, mo);
        ssum = ssum * __expf(m - mn) + so * __expf(mo - mn);
        m = mn;
    }
    const float mx = m;
    const float inv = ssum > 0.f ? 1.f / ssum : 0.f;

    // ---- phase 2: double-buffered 8-edge chunks ----
    const int q = lane & 31;
    const int half = lane >> 5;
    const int hq = q >> 2;
    float a[8] = {};

    int sC = 0; float avC = 0.f;
    if (j < dcap) {
        sC = srcbuf[beg + j];
        float e = el[sC * 8 + h] + ern;
        e = e > 0.f ? e : NEG_SLOPE * e;
        avC = __expf(e - mx) * inv;
    }
    uint4 f[4]; float ae[4];
    #pragma unroll
    for (int u = 0; u < 4; ++u) {
        int sel = hq * 8 + 2 * u + half;
        int se = __shfl(sC, sel);
        ae[u] = __shfl(avC, sel);
        f[u] = *(const uint4*)(feat + (size_t)se * DIM + 8 * q);
    }

    #pragma unroll 2
    for (int c0 = 0; c0 < dcap; c0 += 8) {
        uint4 f2[4]; float ae2[4];
        {
            int sN = 0; float avN = 0.f;
            int i = c0 + 8 + j;
            if (i < dcap) {
                sN = srcbuf[beg + i];
                float e = el[sN * 8 + h] + ern;
                e = e > 0.f ? e : NEG_SLOPE * e;
                avN = __expf(e - mx) * inv;
            }
            #pragma unroll
            for (int u = 0; u < 4; ++u) {
                int sel = hq * 8 + 2 * u + half;
                int se = __shfl(sN, sel);
                ae2[u] = __shfl(avN, sel);
                f2[u] = *(const uint4*)(feat + (size_t)se * DIM + 8 * q);
            }
        }
        #pragma unroll
        for (int u = 0; u < 4; ++u) {
            float wgt = ae[u];
            a[0] += wgt * b2f((u16)(f[u].x & 0xffffu)); a[1] += wgt * b2f((u16)(f[u].x >> 16));
            a[2] += wgt * b2f((u16)(f[u].y & 0xffffu)); a[3] += wgt * b2f((u16)(f[u].y >> 16));
            a[4] += wgt * b2f((u16)(f[u].z & 0xffffu)); a[5] += wgt * b2f((u16)(f[u].z >> 16));
            a[6] += wgt * b2f((u16)(f[u].w & 0xffffu)); a[7] += wgt * b2f((u16)(f[u].w >> 16));
        }
        #pragma unroll
        for (int u = 0; u < 4; ++u) { f[u] = f2[u]; ae[u] = ae2[u]; }
    }

    if (nov) {                               // rare overflow edges
        const float mxq  = __shfl(mx, hq * 8);
        const float invq = __shfl(inv, hq * 8);
        const float ernq = __shfl(ern, hq * 8);
        for (int k = 0; k < nov; ++k) {
            int2 pr = ovf[k];
            if (pr.x != node) continue;
            float av = 0.f;
            if (half == 0) {
                float e = el[pr.y * 8 + hq] + ernq;
                e = e > 0.f ? e : NEG_SLOPE * e;
                av = __expf(e - mxq) * invq;
            }
            uint4 fv = *(const uint4*)(feat + (size_t)pr.y * DIM + 8 * q);
            a[0] += av * b2f((u16)(fv.x & 0xffffu)); a[1] += av * b2f((u16)(fv.x >> 16));
            a[2] += av * b2f((u16)(fv.y & 0xffffu)); a[3] += av * b2f((u16)(fv.y >> 16));
            a[4] += av * b2f((u16)(fv.z & 0xffffu)); a[5] += av * b2f((u16)(fv.z >> 16));
            a[6] += av * b2f((u16)(fv.w & 0xffffu)); a[7] += av * b2f((u16)(fv.w >> 16));
        }
    }

    #pragma unroll
    for (int k = 0; k < 8; ++k) a[k] += __shfl_xor(a[k], 32);

    if (half == 0) {
        float o[8];
        if (isf) {
            float4 b0 = *(const float4*)((const float*)bias + 8 * q);
            float4 b1 = *(const float4*)((const float*)bias + 8 * q + 4);
            o[0] = a[0] + b0.x; o[1] = a[1] + b0.y; o[2] = a[2] + b0.z; o[3] = a[3] + b0.w;
            o[4] = a[4] + b1.x; o[5] = a[5] + b1.y; o[6] = a[6] + b1.z; o[7] = a[7] + b1.w;
        } else {
            uint4 bu = *(const uint4*)((const u16*)bias + 8 * q);
            o[0] = a[0] + b2f((u16)(bu.x & 0xffffu)); o[1] = a[1] + b2f((u16)(bu.x >> 16));
            o[2] = a[2] + b2f((u16)(bu.y & 0xffffu)); o[3] = a[3] + b2f((u16)(bu.y >> 16));
            o[4] = a[4] + b2f((u16)(bu.z & 0xffffu)); o[5] = a[5] + b2f((u16)(bu.z >> 16));
            o[6] = a[6] + b2f((u16)(bu.w & 0xffffu)); o[7] = a[7] + b2f((u16)(bu.w >> 16));
        }
        #pragma unroll
        for (int k = 0; k < 8; ++k) o[k] = fmaxf(o[k], 0.f);
        if (out_mode == 0 || !isf) {
            u16 pk[8] = {f2b(o[0]), f2b(o[1]), f2b(o[2]), f2b(o[3]),
                         f2b(o[4]), f2b(o[5]), f2b(o[6]), f2b(o[7])};
            *(uint4*)((u16*)out + (size_t)node * DIM + 8 * q) = *(uint4*)pk;
        } else {
            float4 v0 = {o[0], o[1], o[2], o[3]};
            float4 v1 = {o[4], o[5], o[6], o[7]};
            *(float4*)((float*)out + (size_t)node * DIM + 8 * q) = v0;
            *(float4*)((float*)out + (size_t)node * DIM + 8 * q + 4) = v1;
        }
    }
}

// ---------------- launch ----------------
extern "C" void kernel_launch(void* const* d_in, const int* in_sizes, int n_in,
                              void* d_out, int out_size, void* d_ws, size_t ws_size,
                              hipStream_t stream) {
    const void* data = d_in[0];
    const int* src = (const int*)d_in[1];
    const int* dst = (const int*)d_in[2];
    const void* W1  = d_in[3];
    const void* al1 = d_in[4];
    const void* ar1 = d_in[5];
    const void* b1  = d_in[6];
    const void* W2  = d_in[7];
    const void* al2 = d_in[8];
    const void* ar2 = d_in[9];
    const void* b2  = d_in[10];

    const size_t BASE =
        (size_t)N_NODES * DIM * 2 +
        (size_t)N_NODES * HEADS * 4 * 2 +
        (size_t)N_NODES * 4 +
        2 * 256 * 256 * 2 +
        1024;
    const size_t NEEDED_PAD = BASE + (size_t)N_NODES * MAXDEG * 4 + (size_t)OVFCAP * 8;
    const size_t NEEDED_CSR = BASE + (size_t)N_NODES * 4 +
                              (size_t)(N_NODES + 4) * 4 +
                              (size_t)N_EDGES * 4;

    if (ws_size < NEEDED_CSR && ws_size < NEEDED_PAD) {
        int nwords = (out_size + 1) / 2;
        fill_u32<<<(nwords + 255) / 256, 256, 0, stream>>>(
            (unsigned int*)d_out, 0x42C842C8u, nwords);
        return;
    }

    char* ws = (char*)d_ws;
    u16* feat = (u16*)ws;        ws += (size_t)N_NODES * DIM * 2;
    float* el = (float*)ws;      ws += (size_t)N_NODES * HEADS * 4;
    float* er = (float*)ws;      ws += (size_t)N_NODES * HEADS * 4;
    int* counts = (int*)ws;      ws += (size_t)N_NODES * 4;
    u16* Wt1 = (u16*)ws;         ws += 256 * 256 * 2;
    u16* Wt2 = (u16*)ws;         ws += 256 * 256 * 2;
    int* flag = (int*)ws;        ws += 256;
    int* novf = (int*)ws;        ws += 256;
    int* partial = (int*)ws;     ws += 256;
    int* offsets = (int*)ws;     ws += 256;

    u16* h1 = (u16*)d_out;
    const int GB = (N_NODES + 31) / 32;     // 1563 gemm blocks (32 rows each)
    const int HALF = 25000;
    const int agg_half_blocks = HALF / 4;

    init_kernel<<<(N_NODES + 255) / 256, 256, 0, stream>>>(
        (const unsigned int*)data, counts, flag, novf);
    prep_kernel<<<32, 256, 0, stream>>>(W1, W2, Wt1, Wt2, flag);

    const int* idxinfo;
    const int* srcbuf;
    const int2* ovf = (const int2*)d_ws;   // placeholder; never read in CSR path (nov=0)
    int pmode;

    if (ws_size >= NEEDED_PAD) {
        int* padded = (int*)ws;  ws += (size_t)N_NODES * MAXDEG * 4;
        int2* ovfw = (int2*)ws;  ws += (size_t)OVFCAP * 8;
        // fused: gemm layer-1 + bucket build, interleaved [g,g,b]
        const int build_blocks = (N_EDGES + 1023) / 1024;            // 782
        const int fused_blocks = 3 * build_blocks;                   // 2346 (gemm slots 1564 >= GB)
        gemm_build_kernel<<<fused_blocks, 256, 0, stream>>>(
            data, 1, Wt1, feat, el, er, al1, ar1, N_NODES, flag,
            src, dst, counts, padded, novf, ovfw, N_EDGES, GB);
        idxinfo = counts; srcbuf = padded; ovf = ovfw; pmode = 1;
    } else {
        int* wptr = (int*)ws;        ws += (size_t)N_NODES * 4;
        int* row_ptr = (int*)ws;     ws += (size_t)(N_NODES + 4) * 4;
        int* src_sorted = (int*)ws;  ws += (size_t)N_EDGES * 4;
        const int nb = (N_NODES + 1023) / 1024;
        hist_kernel<<<(N_EDGES + 255) / 256, 256, 0, stream>>>(dst, counts, N_EDGES);
        scan_partial<<<nb, 256, 0, stream>>>(counts, partial, N_NODES);
        scan_offsets<<<1, 64, 0, stream>>>(partial, offsets, row_ptr, nb, N_NODES);
        scan_write<<<nb, 256, 0, stream>>>(counts, offsets, row_ptr, wptr, N_NODES);
        scatter_kernel<<<(N_EDGES + 255) / 256, 256, 0, stream>>>(src, dst, wptr, src_sorted, N_EDGES);
        idxinfo = row_ptr; srcbuf = src_sorted; pmode = 0;
        gemm_kernel<<<GB, 256, 0, stream>>>(data, 1, Wt1, feat,
                                            el, er, al1, ar1, N_NODES, flag);
    }

    aggregate_kernel<<<agg_half_blocks, 256, 0, stream>>>(feat, el, er, b1, idxinfo, srcbuf,
                                                          (void*)h1, 0, 0, flag, pmode, novf, ovf);
    aggregate_kernel<<<agg_half_blocks, 256, 0, stream>>>(feat, el, er, b1, idxinfo, srcbuf,
                                                          (void*)h1, 0, HALF, flag, pmode, novf, ovf);
    gemm_kernel<<<GB, 256, 0, stream>>>(h1, 0, Wt2, feat,
                                        el, er, al2, ar2, N_NODES, flag);
    aggregate_kernel<<<agg_half_blocks, 256, 0, stream>>>(feat, el, er, b2, idxinfo, srcbuf,
                                                          d_out, 2, 0, flag, pmode, novf, ovf);
    aggregate_kernel<<<agg_half_blocks, 256, 0, stream>>>(feat, el, er, b2, idxinfo, srcbuf,
                                                          d_out, 2, HALF, flag, pmode, novf, ovf);
}

// Round 8
// 375.444 us; speedup vs baseline: 1.1046x; 1.1046x over previous
//
#include <hip/hip_runtime.h>

#define N_NODES 50000
#define N_EDGES 800000
#define DIM 256
#define HEADS 8
#define NEG_SLOPE 0.2f
#define MAXDEG 64
#define OVFCAP 65536

typedef unsigned short u16;
typedef float floatx4 __attribute__((ext_vector_type(4)));
typedef __bf16 bf16x8 __attribute__((ext_vector_type(8)));

__device__ __forceinline__ float b2f(u16 u) {
    union { unsigned int i; float f; } v; v.i = ((unsigned int)u) << 16; return v.f;
}
__device__ __forceinline__ u16 f2b(float f) {
    union { float f; unsigned int i; } v; v.f = f;
    unsigned int x = v.i;
    if ((x & 0x7f800000u) == 0x7f800000u && (x & 0x007fffffu)) {
        return (u16)((x >> 16) | 0x0040u);
    }
    unsigned int r = (x + 0x7fffu + ((x >> 16) & 1u)) >> 16;
    return (u16)r;
}

__global__ __launch_bounds__(256) void fill_u32(unsigned int* __restrict__ p,
                                                unsigned int v, int n) {
    int i = blockIdx.x * 256 + threadIdx.x;
    if (i < n) p[i] = v;
}

// ---- init: zero counts everywhere; block 0 additionally detects dtype ----
__global__ __launch_bounds__(256) void init_kernel(const unsigned int* __restrict__ d,
                                                   int* __restrict__ counts,
                                                   int* __restrict__ flag,
                                                   int* __restrict__ novf) {
    int i = blockIdx.x * 256 + threadIdx.x;
    if (i < N_NODES) counts[i] = 0;
    if (blockIdx.x == 0) {
        __shared__ int cnt;
        if (threadIdx.x == 0) { cnt = 0; *novf = 0; }
        __syncthreads();
        unsigned int w = d[threadIdx.x];
        int bad = 0;
        #pragma unroll
        for (int half = 0; half < 2; ++half) {
            u16 u = (u16)(w >> (16 * half));
            unsigned int e = (u >> 7) & 0xFFu;
            if (u != 0 && (e >= 141u || e <= 27u)) bad = 1;
        }
        atomicAdd(&cnt, bad);
        __syncthreads();
        if (threadIdx.x == 0) *flag = (cnt > 64) ? 1 : 0;   // 1 = fp32 inputs
    }
}

// ---- prep: 32 blocks, LDS-tiled W1/W2 transpose->bf16 ----
__global__ __launch_bounds__(256) void prep_kernel(const void* __restrict__ W1,
                                                   const void* __restrict__ W2,
                                                   u16* __restrict__ Wt1,
                                                   u16* __restrict__ Wt2,
                                                   const int* __restrict__ flagp) {
    const int isf = *flagp;
    int b = blockIdx.x;
    const void* W = (b < 16) ? W1 : W2;
    u16* Wt = (b < 16) ? Wt1 : Wt2;
    int t = b & 15;
    int k0 = (t >> 2) * 64, n0 = (t & 3) * 64;
    __shared__ float lt[64][65];
    int c = threadIdx.x & 63, r0 = threadIdx.x >> 6;
    #pragma unroll
    for (int j = 0; j < 16; ++j) {
        int r = j * 4 + r0;
        lt[r][c] = isf ? ((const float*)W)[(k0 + r) * 256 + n0 + c]
                       : b2f(((const u16*)W)[(k0 + r) * 256 + n0 + c]);
    }
    __syncthreads();
    #pragma unroll
    for (int j = 0; j < 16; ++j) {
        int rn = j * 4 + r0;
        Wt[(n0 + rn) * 256 + k0 + c] = f2b(lt[c][rn]);   // Wt[n][k]=W[k][n]
    }
}

// ---- one-pass padded bucket build: 4 edges/thread, 4 atomics in flight ----
__global__ __launch_bounds__(256) void build_kernel(const int* __restrict__ src,
                                                    const int* __restrict__ dst,
                                                    int* __restrict__ counts,
                                                    int* __restrict__ padded,
                                                    int* __restrict__ novf,
                                                    int2* __restrict__ ovf, int E) {
    int base = blockIdx.x * 1024 + threadIdx.x * 4;
    if (base + 3 < E) {
        int4 d4 = *(const int4*)(dst + base);
        int4 s4 = *(const int4*)(src + base);
        int p0 = atomicAdd(&counts[d4.x], 1);
        int p1 = atomicAdd(&counts[d4.y], 1);
        int p2 = atomicAdd(&counts[d4.z], 1);
        int p3 = atomicAdd(&counts[d4.w], 1);
        if (p0 < MAXDEG) padded[d4.x * MAXDEG + p0] = s4.x;
        else { int oi = atomicAdd(novf, 1); if (oi < OVFCAP) { int2 pr; pr.x = d4.x; pr.y = s4.x; ovf[oi] = pr; } }
        if (p1 < MAXDEG) padded[d4.y * MAXDEG + p1] = s4.y;
        else { int oi = atomicAdd(novf, 1); if (oi < OVFCAP) { int2 pr; pr.x = d4.y; pr.y = s4.y; ovf[oi] = pr; } }
        if (p2 < MAXDEG) padded[d4.z * MAXDEG + p2] = s4.z;
        else { int oi = atomicAdd(novf, 1); if (oi < OVFCAP) { int2 pr; pr.x = d4.z; pr.y = s4.z; ovf[oi] = pr; } }
        if (p3 < MAXDEG) padded[d4.w * MAXDEG + p3] = s4.w;
        else { int oi = atomicAdd(novf, 1); if (oi < OVFCAP) { int2 pr; pr.x = d4.w; pr.y = s4.w; ovf[oi] = pr; } }
    } else {
        for (int k = 0; k < 4; ++k) {
            int i = base + k;
            if (i < E) {
                int d = dst[i], s = src[i];
                int pos = atomicAdd(&counts[d], 1);
                if (pos < MAXDEG) padded[d * MAXDEG + pos] = s;
                else { int oi = atomicAdd(novf, 1); if (oi < OVFCAP) { int2 pr; pr.x = d; pr.y = s; ovf[oi] = pr; } }
            }
        }
    }
}

// ---------------- CSR build (fallback path) ----------------
__global__ __launch_bounds__(256) void hist_kernel(const int* __restrict__ dst,
                                                   int* __restrict__ counts, int E) {
    int i = blockIdx.x * 256 + threadIdx.x;
    if (i < E) atomicAdd(&counts[dst[i]], 1);
}

__global__ __launch_bounds__(256) void scan_partial(const int* __restrict__ counts,
                                                    int* __restrict__ partial, int n) {
    int b = blockIdx.x, tid = threadIdx.x;
    int base = b * 1024 + tid * 4;
    int s = 0;
    #pragma unroll
    for (int k = 0; k < 4; ++k) if (base + k < n) s += counts[base + k];
    int lane = tid & 63;
    #pragma unroll
    for (int off = 32; off; off >>= 1) s += __shfl_xor(s, off);
    __shared__ int wsum[4];
    if (lane == 0) wsum[tid >> 6] = s;
    __syncthreads();
    if (tid == 0) partial[b] = wsum[0] + wsum[1] + wsum[2] + wsum[3];
}

__global__ __launch_bounds__(64) void scan_offsets(const int* __restrict__ partial,
                                                   int* __restrict__ offsets,
                                                   int* __restrict__ row_ptr,
                                                   int nb, int n) {
    int t = threadIdx.x;
    int v0 = (t < nb) ? partial[t] : 0;
    int v = v0;
    #pragma unroll
    for (int d = 1; d < 64; d <<= 1) {
        int u = __shfl_up(v, d);
        if (t >= d) v += u;
    }
    if (t < nb) offsets[t] = v - v0;
    if (t == 63) row_ptr[n] = v;
}

__global__ __launch_bounds__(256) void scan_write(const int* __restrict__ counts,
                                                  const int* __restrict__ offsets,
                                                  int* __restrict__ row_ptr,
                                                  int* __restrict__ wptr, int n) {
    int b = blockIdx.x, tid = threadIdx.x;
    int base = b * 1024 + tid * 4;
    int v[4]; int s = 0;
    #pragma unroll
    for (int k = 0; k < 4; ++k) { v[k] = (base + k < n) ? counts[base + k] : 0; s += v[k]; }
    int lane = tid & 63, w = tid >> 6;
    int incl = s;
    #pragma unroll
    for (int d = 1; d < 64; d <<= 1) {
        int u = __shfl_up(incl, d);
        if (lane >= d) incl += u;
    }
    __shared__ int wsum[4];
    if (lane == 63) wsum[w] = incl;
    __syncthreads();
    int woff = 0;
    for (int i = 0; i < w; ++i) woff += wsum[i];
    int run = offsets[b] + woff + incl - s;
    #pragma unroll
    for (int k = 0; k < 4; ++k) {
        if (base + k < n) { row_ptr[base + k] = run; wptr[base + k] = run; run += v[k]; }
    }
}

__global__ __launch_bounds__(256) void scatter_kernel(const int* __restrict__ src,
                                                      const int* __restrict__ dst,
                                                      int* __restrict__ wptr,
                                                      int* __restrict__ src_sorted, int E) {
    int i = blockIdx.x * 256 + threadIdx.x;
    if (i < E) {
        int pos = atomicAdd(&wptr[dst[i]], 1);
        src_sorted[pos] = src[i];
    }
}

// ---- GEMM (bf16 MFMA) + fused el/er epilogue ----
// Round-4 proven config (45us): A staged once in LDS (fp32->bf16 on the fly),
// B-fragments global->VGPR (Wt 128KB L2-hot) register double-buffered,
// step-0 B hoisted above the staging barrier, no K-loop barriers,
// plain scalar C stores, __launch_bounds__(256,3).
#define LDA 264

__global__ __launch_bounds__(256, 3) void gemm_fused(const void* __restrict__ Araw,
                                                     int maybe_f32,
                                                     const u16* __restrict__ Wt,
                                                     u16* __restrict__ outF,
                                                     float* __restrict__ el,
                                                     float* __restrict__ er,
                                                     const void* __restrict__ al,
                                                     const void* __restrict__ ar,
                                                     int M, const int* __restrict__ flagp) {
    const int isf = *flagp;
    const bool af32 = (maybe_f32 != 0) && (isf != 0);
    __shared__ u16 As[64][LDA];
    const int tid  = threadIdx.x;
    const int w    = tid >> 6;       // wave: n-quarter
    const int lane = tid & 63;
    const int quad = lane >> 4;
    const int l16  = lane & 15;
    const int m0   = blockIdx.x * 64;

    const u16* wbase = Wt + (size_t)(64 * w + l16) * 256 + quad * 8;

    // issue step-0 B loads before the staging barrier (overlap with A staging)
    bf16x8 bCur[4], bNxt[4], aCur[4], aNxt[4];
    #pragma unroll
    for (int t = 0; t < 4; ++t)
        bCur[t] = *(const bf16x8*)(wbase + (size_t)t * 16 * 256);

    if (af32) {
        const float* Af = (const float*)Araw;
        #pragma unroll
        for (int it = 0; it < 8; ++it) {
            int idx = it * 256 + tid;
            int r = idx >> 5;
            int c = (idx & 31) << 3;
            int gr = m0 + r;
            u16 tb[8];
            if (gr < M) {
                float4 f0 = *(const float4*)(Af + (size_t)gr * 256 + c);
                float4 f1 = *(const float4*)(Af + (size_t)gr * 256 + c + 4);
                tb[0] = f2b(f0.x); tb[1] = f2b(f0.y); tb[2] = f2b(f0.z); tb[3] = f2b(f0.w);
                tb[4] = f2b(f1.x); tb[5] = f2b(f1.y); tb[6] = f2b(f1.z); tb[7] = f2b(f1.w);
            } else {
                #pragma unroll
                for (int k = 0; k < 8; ++k) tb[k] = 0;
            }
            *(uint4*)&As[r][c] = *(uint4*)tb;
        }
    } else {
        const u16* Ab = (const u16*)Araw;
        #pragma unroll
        for (int it = 0; it < 8; ++it) {
            int idx = it * 256 + tid;
            int r = idx >> 5;
            int c = (idx & 31) << 3;
            int gr = m0 + r;
            if (gr < M) {
                *(uint4*)&As[r][c] = *(const uint4*)(Ab + (size_t)gr * 256 + c);
            } else {
                uint4 z = {0u, 0u, 0u, 0u};
                *(uint4*)&As[r][c] = z;
            }
        }
    }
    __syncthreads();

    #pragma unroll
    for (int i = 0; i < 4; ++i)
        aCur[i] = *(const bf16x8*)&As[16 * i + l16][quad * 8];

    floatx4 acc[4][4] = {};

    #pragma unroll
    for (int s = 0; s < 8; ++s) {
        if (s < 7) {
            #pragma unroll
            for (int t = 0; t < 4; ++t)
                bNxt[t] = *(const bf16x8*)(wbase + (size_t)t * 16 * 256 + (s + 1) * 32);
            #pragma unroll
            for (int i = 0; i < 4; ++i)
                aNxt[i] = *(const bf16x8*)&As[16 * i + l16][(s + 1) * 32 + quad * 8];
        }
        #pragma unroll
        for (int i = 0; i < 4; ++i)
            #pragma unroll
            for (int t = 0; t < 4; ++t)
                acc[i][t] = __builtin_amdgcn_mfma_f32_16x16x32_bf16(aCur[i], bCur[t], acc[i][t], 0, 0, 0);
        if (s < 7) {
            #pragma unroll
            for (int t = 0; t < 4; ++t) bCur[t] = bNxt[t];
            #pragma unroll
            for (int i = 0; i < 4; ++i) aCur[i] = aNxt[i];
        }
    }

    // C/D: col = l16, row = quad*4+r (within 16x16 slice) — direct scalar stores
    #pragma unroll
    for (int i = 0; i < 4; ++i)
        #pragma unroll
        for (int t = 0; t < 4; ++t)
            #pragma unroll
            for (int r = 0; r < 4; ++r) {
                int row = m0 + 16 * i + quad * 4 + r;
                if (row < M) outF[(size_t)row * 256 + 64 * w + 16 * t + l16] = f2b(acc[i][t][r]);
            }

    // fused el/er: wave w covers heads 2w, 2w+1
    float alv[4], arv[4];
    #pragma unroll
    for (int t = 0; t < 4; ++t) {
        int c = 64 * w + 16 * t + l16;
        alv[t] = isf ? ((const float*)al)[c] : b2f(((const u16*)al)[c]);
        arv[t] = isf ? ((const float*)ar)[c] : b2f(((const u16*)ar)[c]);
    }
    #pragma unroll
    for (int i = 0; i < 4; ++i)
        #pragma unroll
        for (int r = 0; r < 4; ++r) {
            int row = m0 + 16 * i + quad * 4 + r;
            #pragma unroll
            for (int tt = 0; tt < 2; ++tt) {
                float pl = acc[i][2 * tt][r] * alv[2 * tt] + acc[i][2 * tt + 1][r] * alv[2 * tt + 1];
                float pr = acc[i][2 * tt][r] * arv[2 * tt] + acc[i][2 * tt + 1][r] * arv[2 * tt + 1];
                #pragma unroll
                for (int mask = 1; mask <= 8; mask <<= 1) {
                    pl += __shfl_xor(pl, mask);
                    pr += __shfl_xor(pr, mask);
                }
                if (l16 == 0 && row < M) {
                    el[row * 8 + 2 * w + tt] = pl;
                    er[row * 8 + 2 * w + tt] = pr;
                }
            }
        }
}

// ---- aggregate: 1 wave/node, full range; pmode=1 padded buckets, pmode=0 CSR ----
__global__ __launch_bounds__(256) void aggregate_kernel(const u16* __restrict__ feat,
                                                        const float* __restrict__ el,
                                                        const float* __restrict__ er,
                                                        const void* __restrict__ bias,
                                                        const int* __restrict__ idxinfo,
                                                        const int* __restrict__ srcbuf,
                                                        void* __restrict__ out,
                                                        int out_mode,
                                                        const int* __restrict__ flagp,
                                                        int pmode,
                                                        const int* __restrict__ novfp,
                                                        const int2* __restrict__ ovf) {
    const int isf = *flagp;
    const int lane = threadIdx.x & 63;
    const int node = blockIdx.x * 4 + (threadIdx.x >> 6);
    if (node >= N_NODES) return;
    const int h = lane >> 3;
    const int j = lane & 7;
    int beg, deg;
    if (pmode) { beg = node * MAXDEG; deg = idxinfo[node]; }
    else       { beg = idxinfo[node]; deg = idxinfo[node + 1] - beg; }
    const int dcap = (pmode && deg > MAXDEG) ? MAXDEG : deg;
    int nov = 0;
    if (pmode && deg > MAXDEG) { nov = *novfp; if (nov > OVFCAP) nov = OVFCAP; }
    const float ern = er[node * HEADS + h];

    // ---- phase 1: online softmax, 2 independent accumulators (ILP) ----
    float m0v = -1e30f, ss0 = 0.f;
    float m1v = -1e30f, ss1 = 0.f;
    for (int i = j; i < dcap; i += 16) {
        int s0 = srcbuf[beg + i];
        int i2 = i + 8;
        int s1 = (i2 < dcap) ? srcbuf[beg + i2] : 0;
        float e0 = el[s0 * 8 + h] + ern;
        float e1 = el[s1 * 8 + h] + ern;
        e0 = e0 > 0.f ? e0 : NEG_SLOPE * e0;
        e1 = e1 > 0.f ? e1 : NEG_SLOPE * e1;
        if (i2 >= dcap) e1 = -3e30f;
        float mn0 = fmaxf(m0v, e0);
        ss0 = ss0 * __expf(m0v - mn0) + __expf(e0 - mn0);
        m0v = mn0;
        float mn1 = fmaxf(m1v, e1);
        ss1 = ss1 * __expf(m1v - mn1) + __expf(e1 - mn1);
        m1v = mn1;
    }
    for (int k = j; k < nov; k += 8) {       // rare overflow edges
        int2 pr = ovf[k];
        if (pr.x != node) continue;
        float e = el[pr.y * 8 + h] + ern;
        e = e > 0.f ? e : NEG_SLOPE * e;
        float mn = fmaxf(m0v, e);
        ss0 = ss0 * __expf(m0v - mn) + __expf(e - mn);
        m0v = mn;
    }
    float m = fmaxf(m0v, m1v);
    float ssum = ss0 * __expf(m0v - m) + ss1 * __expf(m1v - m);
    #pragma unroll
    for (int mask = 1; mask <= 4; mask <<= 1) {
        float mo = __shfl_xor(m, mask);
        float so = __shfl_xor(ssum, mask);
        float mn = fmaxf(m, mo);
        ssum = ssum * __expf(m - mn) + so * __expf(mo - mn);
        m = mn;
    }
    const float mx = m;
    const float inv = ssum > 0.f ? 1.f / ssum : 0.f;

    // ---- phase 2: double-buffered 8-edge chunks ----
    const int q = lane & 31;
    const int half = lane >> 5;
    const int hq = q >> 2;
    float a[8] = {};

    int sC = 0; float avC = 0.f;
    if (j < dcap) {
        sC = srcbuf[beg + j];
        float e = el[sC * 8 + h] + ern;
        e = e > 0.f ? e : NEG_SLOPE * e;
        avC = __expf(e - mx) * inv;
    }
    uint4 f[4]; float ae[4];
    #pragma unroll
    for (int u = 0; u < 4; ++u) {
        int sel = hq * 8 + 2 * u + half;
        int se = __shfl(sC, sel);
        ae[u] = __shfl(avC, sel);
        f[u] = *(const uint4*)(feat + (size_t)se * DIM + 8 * q);
    }

    #pragma unroll 2
    for (int c0 = 0; c0 < dcap; c0 += 8) {
        uint4 f2[4]; float ae2[4];
        {
            int sN = 0; float avN = 0.f;
            int i = c0 + 8 + j;
            if (i < dcap) {
                sN = srcbuf[beg + i];
                float e = el[sN * 8 + h] + ern;
                e = e > 0.f ? e : NEG_SLOPE * e;
                avN = __expf(e - mx) * inv;
            }
            #pragma unroll
            for (int u = 0; u < 4; ++u) {
                int sel = hq * 8 + 2 * u + half;
                int se = __shfl(sN, sel);
                ae2[u] = __shfl(avN, sel);
                f2[u] = *(const uint4*)(feat + (size_t)se * DIM + 8 * q);
            }
        }
        #pragma unroll
        for (int u = 0; u < 4; ++u) {
            float wgt = ae[u];
            a[0] += wgt * b2f((u16)(f[u].x & 0xffffu)); a[1] += wgt * b2f((u16)(f[u].x >> 16));
            a[2] += wgt * b2f((u16)(f[u].y & 0xffffu)); a[3] += wgt * b2f((u16)(f[u].y >> 16));
            a[4] += wgt * b2f((u16)(f[u].z & 0xffffu)); a[5] += wgt * b2f((u16)(f[u].z >> 16));
            a[6] += wgt * b2f((u16)(f[u].w & 0xffffu)); a[7] += wgt * b2f((u16)(f[u].w >> 16));
        }
        #pragma unroll
        for (int u = 0; u < 4; ++u) { f[u] = f2[u]; ae[u] = ae2[u]; }
    }

    if (nov) {                               // rare overflow edges
        const float mxq  = __shfl(mx, hq * 8);
        const float invq = __shfl(inv, hq * 8);
        const float ernq = __shfl(ern, hq * 8);
        for (int k = 0; k < nov; ++k) {
            int2 pr = ovf[k];
            if (pr.x != node) continue;
            float av = 0.f;
            if (half == 0) {
                float e = el[pr.y * 8 + hq] + ernq;
                e = e > 0.f ? e : NEG_SLOPE * e;
                av = __expf(e - mxq) * invq;
            }
            uint4 fv = *(const uint4*)(feat + (size_t)pr.y * DIM + 8 * q);
            a[0] += av * b2f((u16)(fv.x & 0xffffu)); a[1] += av * b2f((u16)(fv.x >> 16));
            a[2] += av * b2f((u16)(fv.y & 0xffffu)); a[3] += av * b2f((u16)(fv.y >> 16));
            a[4] += av * b2f((u16)(fv.z & 0xffffu)); a[5] += av * b2f((u16)(fv.z >> 16));
            a[6] += av * b2f((u16)(fv.w & 0xffffu)); a[7] += av * b2f((u16)(fv.w >> 16));
        }
    }

    #pragma unroll
    for (int k = 0; k < 8; ++k) a[k] += __shfl_xor(a[k], 32);

    if (half == 0) {
        float o[8];
        if (isf) {
            float4 b0 = *(const float4*)((const float*)bias + 8 * q);
            float4 b1 = *(const float4*)((const float*)bias + 8 * q + 4);
            o[0] = a[0] + b0.x; o[1] = a[1] + b0.y; o[2] = a[2] + b0.z; o[3] = a[3] + b0.w;
            o[4] = a[4] + b1.x; o[5] = a[5] + b1.y; o[6] = a[6] + b1.z; o[7] = a[7] + b1.w;
        } else {
            uint4 bu = *(const uint4*)((const u16*)bias + 8 * q);
            o[0] = a[0] + b2f((u16)(bu.x & 0xffffu)); o[1] = a[1] + b2f((u16)(bu.x >> 16));
            o[2] = a[2] + b2f((u16)(bu.y & 0xffffu)); o[3] = a[3] + b2f((u16)(bu.y >> 16));
            o[4] = a[4] + b2f((u16)(bu.z & 0xffffu)); o[5] = a[5] + b2f((u16)(bu.z >> 16));
            o[6] = a[6] + b2f((u16)(bu.w & 0xffffu)); o[7] = a[7] + b2f((u16)(bu.w >> 16));
        }
        #pragma unroll
        for (int k = 0; k < 8; ++k) o[k] = fmaxf(o[k], 0.f);
        if (out_mode == 0 || !isf) {
            u16 pk[8] = {f2b(o[0]), f2b(o[1]), f2b(o[2]), f2b(o[3]),
                         f2b(o[4]), f2b(o[5]), f2b(o[6]), f2b(o[7])};
            *(uint4*)((u16*)out + (size_t)node * DIM + 8 * q) = *(uint4*)pk;
        } else {
            float4 v0 = {o[0], o[1], o[2], o[3]};
            float4 v1 = {o[4], o[5], o[6], o[7]};
            *(float4*)((float*)out + (size_t)node * DIM + 8 * q) = v0;
            *(float4*)((float*)out + (size_t)node * DIM + 8 * q + 4) = v1;
        }
    }
}

// ---------------- launch ----------------
extern "C" void kernel_launch(void* const* d_in, const int* in_sizes, int n_in,
                              void* d_out, int out_size, void* d_ws, size_t ws_size,
                              hipStream_t stream) {
    const void* data = d_in[0];
    const int* src = (const int*)d_in[1];
    const int* dst = (const int*)d_in[2];
    const void* W1  = d_in[3];
    const void* al1 = d_in[4];
    const void* ar1 = d_in[5];
    const void* b1  = d_in[6];
    const void* W2  = d_in[7];
    const void* al2 = d_in[8];
    const void* ar2 = d_in[9];
    const void* b2  = d_in[10];

    const size_t BASE =
        (size_t)N_NODES * DIM * 2 +
        (size_t)N_NODES * HEADS * 4 * 2 +
        (size_t)N_NODES * 4 +
        2 * 256 * 256 * 2 +
        1024;
    const size_t NEEDED_PAD = BASE + (size_t)N_NODES * MAXDEG * 4 + (size_t)OVFCAP * 8;
    const size_t NEEDED_CSR = BASE + (size_t)N_NODES * 4 +
                              (size_t)(N_NODES + 4) * 4 +
                              (size_t)N_EDGES * 4;

    if (ws_size < NEEDED_CSR && ws_size < NEEDED_PAD) {
        int nwords = (out_size + 1) / 2;
        fill_u32<<<(nwords + 255) / 256, 256, 0, stream>>>(
            (unsigned int*)d_out, 0x42C842C8u, nwords);
        return;
    }

    char* ws = (char*)d_ws;
    u16* feat = (u16*)ws;        ws += (size_t)N_NODES * DIM * 2;
    float* el = (float*)ws;      ws += (size_t)N_NODES * HEADS * 4;
    float* er = (float*)ws;      ws += (size_t)N_NODES * HEADS * 4;
    int* counts = (int*)ws;      ws += (size_t)N_NODES * 4;
    u16* Wt1 = (u16*)ws;         ws += 256 * 256 * 2;
    u16* Wt2 = (u16*)ws;         ws += 256 * 256 * 2;
    int* flag = (int*)ws;        ws += 256;
    int* novf = (int*)ws;        ws += 256;
    int* partial = (int*)ws;     ws += 256;
    int* offsets = (int*)ws;     ws += 256;

    u16* h1 = (u16*)d_out;
    const int gemm_blocks = (N_NODES + 63) / 64;    // 782
    const int agg_blocks = (N_NODES + 3) / 4;       // 12500

    init_kernel<<<(N_NODES + 255) / 256, 256, 0, stream>>>(
        (const unsigned int*)data, counts, flag, novf);
    prep_kernel<<<32, 256, 0, stream>>>(W1, W2, Wt1, Wt2, flag);

    const int* idxinfo;
    const int* srcbuf;
    const int2* ovf = (const int2*)d_ws;   // placeholder; never read in CSR path (nov=0)
    int pmode;

    if (ws_size >= NEEDED_PAD) {
        int* padded = (int*)ws;  ws += (size_t)N_NODES * MAXDEG * 4;
        int2* ovfw = (int2*)ws;  ws += (size_t)OVFCAP * 8;
        build_kernel<<<(N_EDGES + 1023) / 1024, 256, 0, stream>>>(
            src, dst, counts, padded, novf, ovfw, N_EDGES);
        idxinfo = counts; srcbuf = padded; ovf = ovfw; pmode = 1;
    } else {
        int* wptr = (int*)ws;        ws += (size_t)N_NODES * 4;
        int* row_ptr = (int*)ws;     ws += (size_t)(N_NODES + 4) * 4;
        int* src_sorted = (int*)ws;  ws += (size_t)N_EDGES * 4;
        const int nb = (N_NODES + 1023) / 1024;
        hist_kernel<<<(N_EDGES + 255) / 256, 256, 0, stream>>>(dst, counts, N_EDGES);
        scan_partial<<<nb, 256, 0, stream>>>(counts, partial, N_NODES);
        scan_offsets<<<1, 64, 0, stream>>>(partial, offsets, row_ptr, nb, N_NODES);
        scan_write<<<nb, 256, 0, stream>>>(counts, offsets, row_ptr, wptr, N_NODES);
        scatter_kernel<<<(N_EDGES + 255) / 256, 256, 0, stream>>>(src, dst, wptr, src_sorted, N_EDGES);
        idxinfo = row_ptr; srcbuf = src_sorted; pmode = 0;
    }

    gemm_fused<<<gemm_blocks, 256, 0, stream>>>(data, 1, Wt1, feat,
                                                el, er, al1, ar1, N_NODES, flag);
    aggregate_kernel<<<agg_blocks, 256, 0, stream>>>(feat, el, er, b1, idxinfo, srcbuf,
                                                     (void*)h1, 0, flag, pmode, novf, ovf);
    gemm_fused<<<gemm_blocks, 256, 0, stream>>>(h1, 0, Wt2, feat,
                                                el, er, al2, ar2, N_NODES, flag);
    aggregate_kernel<<<agg_blocks, 256, 0, stream>>>(feat, el, er, b2, idxinfo, srcbuf,
                                                     d_out, 2, flag, pmode, novf, ovf);
}